// Round 7
// baseline (497.517 us; speedup 1.0000x reference)
//
#include <hip/hip_runtime.h>
#include <math.h>

// Reference is fp32: all d_in are const float*, d_out is float*.
// Internal compute in bf16 (threshold = 2% of |ref|max permits it).
// B=4 S=2048 H=16 DH=64 D=1024; FF_IN=4096 FF_HID=2048.

typedef __bf16 bf16;
typedef bf16 bf16x8 __attribute__((ext_vector_type(8)));
typedef bf16 bf16x4 __attribute__((ext_vector_type(4)));
typedef float f32x4 __attribute__((ext_vector_type(4)));

#define MFMA(a, b, c) __builtin_amdgcn_mfma_f32_16x16x32_bf16(a, b, c, 0, 0, 0)

// Async global->LDS, 16B/lane; LDS dest = wave-uniform base + lane*16.
// XOR-swizzle is applied on the GLOBAL source index so the LDS image is
// swizzled; reads apply the same XOR.
__device__ __forceinline__ void async16(const void* g, void* l) {
    __builtin_amdgcn_global_load_lds(
        (const __attribute__((address_space(1))) void*)g,
        (__attribute__((address_space(3))) void*)l,
        16, 0, 0);
}

// ---------------------------------------------------------------------------
// Diagnostic: fill out with 0.25 if ws_size too small (absmax ~5.31, not NaN).
// ---------------------------------------------------------------------------
__global__ __launch_bounds__(256) void fill_sentinel(float* __restrict__ o)
{
    size_t i = ((size_t)blockIdx.x * 256 + threadIdx.x) * 4;
    *(float4*)&o[i] = make_float4(0.25f, 0.25f, 0.25f, 0.25f);
}

// ---------------------------------------------------------------------------
// fp32 -> bf16 elementwise (for QKV GEMM A operand). 8 elems/thread.
// ---------------------------------------------------------------------------
__global__ __launch_bounds__(256) void convert_f32_bf16(
    const float* __restrict__ in, bf16* __restrict__ out)
{
    size_t i = ((size_t)blockIdx.x * 256 + threadIdx.x) * 8;
    float4 f0 = *(const float4*)&in[i];
    float4 f1 = *(const float4*)&in[i + 4];
    bf16x8 v;
    v[0] = (bf16)f0.x; v[1] = (bf16)f0.y; v[2] = (bf16)f0.z; v[3] = (bf16)f0.w;
    v[4] = (bf16)f1.x; v[5] = (bf16)f1.y; v[6] = (bf16)f1.z; v[7] = (bf16)f1.w;
    *(bf16x8*)&out[i] = v;
}

// ---------------------------------------------------------------------------
// Weight transpose + convert: fp32 [K][N] -> bf16 [N][K], 64x64 tiles.
// ---------------------------------------------------------------------------
__global__ __launch_bounds__(256) void transpose_f32_bf16(
    const float* __restrict__ in, bf16* __restrict__ out, int K, int N)
{
    __shared__ bf16 T[64][70];
    const int tN = N >> 6;
    const int tk = blockIdx.x / tN, tn = blockIdx.x % tN;
    const int k0 = tk << 6, n0 = tn << 6;
    const int t = threadIdx.x;
    const int r = t >> 2, c0 = (t & 3) << 4;
    const float* src = &in[(size_t)(k0 + r) * N + n0 + c0];
    for (int j = 0; j < 4; ++j) {
        float4 f = *(const float4*)(src + 4 * j);
        T[r][c0 + 4 * j + 0] = (bf16)f.x;
        T[r][c0 + 4 * j + 1] = (bf16)f.y;
        T[r][c0 + 4 * j + 2] = (bf16)f.z;
        T[r][c0 + 4 * j + 3] = (bf16)f.w;
    }
    __syncthreads();
    bf16x8 o0, o1;
    for (int i = 0; i < 8; ++i) o0[i] = T[c0 + i][r];
    for (int i = 0; i < 8; ++i) o1[i] = T[c0 + 8 + i][r];
    *(bf16x8*)&out[(size_t)(n0 + r) * K + k0 + c0]     = o0;
    *(bf16x8*)&out[(size_t)(n0 + r) * K + k0 + c0 + 8] = o1;
}

// ---------------------------------------------------------------------------
// V transpose: in[bh][s][d] -> out[bh][d][s] (bh=64, s=2048, d=64), bf16.
// ---------------------------------------------------------------------------
__global__ __launch_bounds__(256) void transpose_v(
    const bf16* __restrict__ in, bf16* __restrict__ out)
{
    __shared__ bf16 T[64][72];
    const int bh = blockIdx.x >> 5;
    const int s0 = (blockIdx.x & 31) << 6;
    const bf16* ip = in + ((size_t)bh << 17) + (size_t)s0 * 64;
    bf16* op = out + ((size_t)bh << 17) + s0;
    const int t = threadIdx.x;
    const int r = t >> 2, c0 = (t & 3) << 4;
    *(bf16x8*)&T[r][c0]     = *(const bf16x8*)&ip[r * 64 + c0];
    *(bf16x8*)&T[r][c0 + 8] = *(const bf16x8*)&ip[r * 64 + c0 + 8];
    __syncthreads();
    bf16x8 o0, o1;
    for (int i = 0; i < 8; ++i) o0[i] = T[c0 + i][r];
    for (int i = 0; i < 8; ++i) o1[i] = T[c0 + 8 + i][r];
    *(bf16x8*)&op[(size_t)r * 2048 + c0]     = o0;
    *(bf16x8*)&op[(size_t)r * 2048 + c0 + 8] = o1;
}

// ---------------------------------------------------------------------------
// 256xBN GEMM, 8 waves (512 thr), BK=64, double-buffered LDS, depth-2
// prefetch with counted vmcnt (never 0 in steady state) and raw s_barrier.
// Chunk XOR-swizzle. Wave grid 2Mx4N. A row stride = lda; BT row stride = K.
// Requires M%256==0, K%128==0, grid%8==0.
//
// EPI 0: scatter qkv -> C0/C1/C2 as [B,H,S,DH]
// EPI 1: bf16 C0[row*N+col]
// EPI 2: fp32 Cf[row*N+col] = v + resid (resid bf16)
// EPI 3: FUSED SwiGLU. BN=256; block covers x-cols [n0,n0+128) (B rows
//        0..127 = W1T rows n0+r) and gate-cols [2048+n0,2048+n0+128)
//        (B rows 128..255 = W1T rows n0+1920+r). Wave wn owns x cols
//        wn*32+ni*16+l16 (ni 0,1) and the SAME cols' gates (ni 2,3).
//        Epilogue writes silu(g)*x -> C0 as [M][2048] bf16 (N param = 2048).
// ---------------------------------------------------------------------------
template <int BN, bool SPLIT>
__device__ __forceinline__ void g256_stage(
    const bf16* __restrict__ Ag, const bf16* __restrict__ Bg, int kt,
    int lda, int K, char* aB, char* bB, int tid, int wave)
{
    for (int i = 0; i < 4; ++i) {               // A: 256 rows = 2048 chunks
        int l = (i << 9) + tid;
        int r = l >> 3;
        int cbs = ((l & 7) ^ (r & 7)) << 3;     // swizzled source column
        int cu = (i << 9) + (wave << 6);        // wave-uniform chunk base
        async16(&Ag[(size_t)r * lda + kt + cbs], aB + (size_t)cu * 16);
    }
    for (int i = 0; i < BN / 64; ++i) {         // B: BN rows = BN*8 chunks
        int l = (i << 9) + tid;
        int r = l >> 3;
        int cbs = ((l & 7) ^ (r & 7)) << 3;
        int cu = (i << 9) + (wave << 6);
        size_t grow = SPLIT ? (size_t)(r + ((r >> 7) * 1920)) : (size_t)r;
        async16(&Bg[grow * K + kt + cbs], bB + (size_t)cu * 16);
    }
}

template <int NI, bool SPLIT>
__device__ __forceinline__ void g256_compute(
    const bf16* At, const bf16* Bt, f32x4 (&acc)[8][NI],
    int wm, int wn, int l16, int quad, int rsw)
{
    for (int kd = 0; kd < 2; ++kd) {
        bf16x8 af[8], bfr[NI];
        for (int mi = 0; mi < 8; ++mi) {
            int row = (wm << 7) + (mi << 4) + l16;
            af[mi] = *(const bf16x8*)&At[(row << 6) + ((((kd << 2) + quad) ^ rsw) << 3)];
        }
        for (int ni = 0; ni < NI; ++ni) {
            int row;
            if (SPLIT)   // ni 0,1 = x rows [0,128); ni 2,3 = gate rows [128,256)
                row = ((ni >= 2) ? 128 : 0) + (wn << 5) + ((ni & 1) << 4) + l16;
            else
                row = wn * (NI << 4) + (ni << 4) + l16;
            bfr[ni] = *(const bf16x8*)&Bt[(row << 6) + ((((kd << 2) + quad) ^ rsw) << 3)];
        }
        __builtin_amdgcn_s_setprio(1);
        for (int mi = 0; mi < 8; ++mi)
            for (int ni = 0; ni < NI; ++ni)
                acc[mi][ni] = MFMA(af[mi], bfr[ni], acc[mi][ni]);
        __builtin_amdgcn_s_setprio(0);
    }
}

#define G256_WAIT()                                                        \
    if constexpr (BN == 256) asm volatile("s_waitcnt vmcnt(8)" ::: "memory"); \
    else                     asm volatile("s_waitcnt vmcnt(6)" ::: "memory")

template <int EPI, int BN>
__global__ __launch_bounds__(512, 2) void gemm256(
    const bf16* __restrict__ A, const bf16* __restrict__ BT,
    const float* __restrict__ bias, int M, int N, int K, int lda,
    bf16* __restrict__ C0, bf16* __restrict__ C1, bf16* __restrict__ C2,
    float* __restrict__ Cf, const bf16* __restrict__ resid)
{
    constexpr int NI = BN / 64;                 // ni count per wave
    constexpr bool SPLIT = (EPI == 3);
    constexpr int TILE_N = SPLIT ? 128 : BN;    // output cols per block
    __shared__ bf16 As[2][256 * 64];
    __shared__ bf16 Bs[2][BN * 64];
    const int tid = threadIdx.x;
    const int lane = tid & 63, wave = tid >> 6;
    const int quad = lane >> 4, l16 = lane & 15;
    const int rsw = l16 & 7;
    const int wm = wave >> 2, wn = wave & 3;    // 2 x 4 wave grid
    const int nb = N / TILE_N;
    const int nwg = gridDim.x;                  // grid % 8 == 0 (caller)
    const int bid = blockIdx.x;
    const int swz = (bid & 7) * (nwg >> 3) + (bid >> 3);   // XCD-chunked
    const int bm = swz / nb, bn = swz % nb;
    const int m0 = bm << 8, n0 = bn * TILE_N;
    const bf16* Ag = A + (size_t)m0 * lda;
    const bf16* Bg = BT + (size_t)n0 * K;
    char* a0 = (char*)&As[0][0]; char* a1 = (char*)&As[1][0];
    char* b0 = (char*)&Bs[0][0]; char* b1 = (char*)&Bs[1][0];

    f32x4 acc[8][NI] = {};
    const int NT = K >> 6;                      // even (K%128==0)

    g256_stage<BN, SPLIT>(Ag, Bg, 0,  lda, K, a0, b0, tid, wave);
    g256_stage<BN, SPLIT>(Ag, Bg, 64, lda, K, a1, b1, tid, wave);
    G256_WAIT();                                // tile 0 resident
    __builtin_amdgcn_s_barrier();

    for (int t = 0; t < NT; t += 2) {
        // even tile -> buf 0
        g256_compute<NI, SPLIT>(&As[0][0], &Bs[0][0], acc, wm, wn, l16, quad, rsw);
        asm volatile("" ::: "memory");
        __builtin_amdgcn_s_barrier();
        if (t + 2 < NT) {
            g256_stage<BN, SPLIT>(Ag, Bg, (t + 2) << 6, lda, K, a0, b0, tid, wave);
            G256_WAIT();
        } else {
            asm volatile("s_waitcnt vmcnt(0)" ::: "memory");
        }
        __builtin_amdgcn_s_barrier();
        // odd tile -> buf 1
        g256_compute<NI, SPLIT>(&As[1][0], &Bs[1][0], acc, wm, wn, l16, quad, rsw);
        asm volatile("" ::: "memory");
        __builtin_amdgcn_s_barrier();
        if (t + 3 < NT) {
            g256_stage<BN, SPLIT>(Ag, Bg, (t + 3) << 6, lda, K, a1, b1, tid, wave);
            G256_WAIT();
        } else {
            asm volatile("s_waitcnt vmcnt(0)" ::: "memory");
        }
        __builtin_amdgcn_s_barrier();
    }

    if (EPI == 3) {
        for (int mi = 0; mi < 8; ++mi) {
            for (int ni = 0; ni < 2; ++ni) {
                for (int r = 0; r < 4; ++r) {
                    int row  = m0 + (wm << 7) + (mi << 4) + (quad << 2) + r;
                    int colx = n0 + (wn << 5) + (ni << 4) + l16;
                    float x = acc[mi][ni][r]     + bias[colx];
                    float g = acc[mi][ni + 2][r] + bias[2048 + colx];
                    float s = g / (1.0f + __expf(-g)) * x;
                    C0[(size_t)row * N + colx] = (bf16)s;
                }
            }
        }
        return;
    }

    for (int mi = 0; mi < 8; ++mi) {
        for (int ni = 0; ni < NI; ++ni) {
            for (int r = 0; r < 4; ++r) {
                int row = m0 + (wm << 7) + (mi << 4) + (quad << 2) + r;
                int col = n0 + wn * (NI << 4) + (ni << 4) + l16;
                float v = acc[mi][ni][r] + bias[col];
                if (EPI == 0) {
                    int b = row >> 11, s = row & 2047;
                    int h = col / 192, w = col % 192;
                    int tq = w >> 6, d = w & 63;
                    bf16* dst = (tq == 0) ? C0 : (tq == 1) ? C1 : C2;
                    dst[((((size_t)b * 16 + h) * 2048 + s) << 6) + d] = (bf16)v;
                } else if (EPI == 1) {
                    C0[(size_t)row * N + col] = (bf16)v;
                } else {
                    float rv = (float)resid[(size_t)row * N + col];
                    Cf[(size_t)row * N + col] = v + rv;
                }
            }
        }
    }
}

// ---------------------------------------------------------------------------
// Fused l2norm + head-scale + xpos RoPE, in place, HW transcendentals.
// ---------------------------------------------------------------------------
__global__ __launch_bounds__(256) void norm_rope(
    bf16* __restrict__ qb, bf16* __restrict__ kb,
    const float* __restrict__ qs, const float* __restrict__ ks)
{
    const int wave = threadIdx.x >> 6, lane = threadIdx.x & 63;
    const int rid = blockIdx.x * 4 + wave;          // 0 .. 262143
    const bool is_k = rid >= 131072;
    const int idx = is_k ? rid - 131072 : rid;      // bh*2048 + s
    const int s = idx & 2047;
    bf16* ptr = (is_k ? kb : qb) + ((size_t)idx << 6);
    const int d = lane;

    float v = (float)ptr[d];
    float ss = v * v;
    for (int o = 1; o < 64; o <<= 1) ss += __shfl_xor(ss, o);
    float t = v * rsqrtf(fmaxf(ss, 1e-24f));
    t *= (is_k ? ks : qs)[d];

    float partner = __shfl_xor(t, 32);
    float rh = (d < 32) ? -partner : partner;       // rotate_half

    const float fi = (float)(d & 31);
    float inv_freq = __builtin_amdgcn_exp2f(fi * -0.4152410118609203f);
    float pos = (float)s * inv_freq;
    float rev = pos * 0.15915494309189535f;         // v_sin takes revolutions
    rev = rev - floorf(rev);
    float sn = __builtin_amdgcn_sinf(rev);
    float cs = __builtin_amdgcn_cosf(rev);
    float base = (2.0f * fi + 25.6f) * (1.0f / 89.6f);
    float power = ((float)s - 1024.0f) * (1.0f / 512.0f);
    if (is_k) power = -power;
    float xsc = __builtin_amdgcn_exp2f(power * __builtin_amdgcn_logf(base));
    ptr[d] = (bf16)((t * cs + rh * sn) * xsc);
}

// ---------------------------------------------------------------------------
// Flash attention, no-max softmax (|score|/8 <= ~19 -> exp <= 1.4e8, fp32-safe;
// 0.125*log2e folded into Q; P = exp2). Row-sums via ones-column MFMA.
// Block = (bh, 128 q-rows); wave owns 32 rows (2 subtiles).
//
// ZERO-MOVEMENT P (R4): permuted Ks rows make the swapped-QK^T output land
// exactly in the PV A-fragment; exp2 feeds MFMA operands directly.
// bh-clustered XCD remap (R6): FETCH 139 -> 24.6 MB.
//
// R7: counted-vmcnt pipeline (T3+T4, ported from gemm256). __syncthreads'
// implicit vmcnt(0) was force-draining the t+1 prefetch after only ~400cyc
// of compute (< load latency) -> exposed stall every tile, pinning attn at
// ~100us across R1-R6. Now: 3-buffer ring, depth-2 prefetch, raw s_barrier,
// vmcnt(8) (stage = 4 loads/thread; 8 = tiles t+1,t+2 in flight, drains t).
// Tile t's loads get a 2-iteration window to land. Q-fragment loads are
// drained by an explicit vmcnt(0) BEFORE the prologue stages so the loop's
// scoreboard counts only staging loads. Read-before-overwrite safety: every
// ds_read is consumed by an MFMA before the trailing barrier (lgkmcnt
// naturally drained), same argument as gemm256.
// ---------------------------------------------------------------------------
__device__ __forceinline__ int swz_a(int r) {
    int a = (r >> 3) & 3;
    return (r & 7) ^ a ^ ((a << 1) & 7);
}

__device__ __forceinline__ void attn_stage(
    const bf16* __restrict__ Kp, const bf16* __restrict__ Vp, int kt,
    char* kB, char* vB, int tid, int wave)
{
    for (int i = 0; i < 2; ++i) {
        int l = (i << 8) + tid;
        int r = l >> 3;
        int cbs = ((l & 7) ^ swz_a(r)) << 3;
        int cu = (i << 8) + (wave << 6);
        async16(&Kp[(size_t)(kt + r) * 64 + cbs], kB + (size_t)cu * 16);
        async16(&Vp[(size_t)r * 2048 + kt + cbs], vB + (size_t)cu * 16);
    }
}

__global__ __launch_bounds__(256) void attn(
    const bf16* __restrict__ Q, const bf16* __restrict__ Kb,
    const bf16* __restrict__ VT, bf16* __restrict__ O)
{
    __shared__ bf16 Ks[3][64 * 64];
    __shared__ bf16 Vt[3][64 * 64];       // Vt[d][j] image (swizzled chunks)
    const int tid = threadIdx.x;
    const int lane = tid & 63, wave = tid >> 6;
    const int quad = lane >> 4, l16 = lane & 15;
    const int wgi = blockIdx.x;
    const int rr = wgi >> 3;
    const int bh = ((wgi & 7) << 3) + (rr >> 4);   // bh-clustered per XCD
    const int q0 = (rr & 15) << 7;
    const int s_base = q0 + (wave << 5);
    const bf16* Qp = Q + ((size_t)bh << 17);
    const bf16* Kp = Kb + ((size_t)bh << 17);
    const bf16* Vp = VT + ((size_t)bh << 17);

    bf16x8 qf[2][2];
    for (int sub = 0; sub < 2; ++sub) {
        const bf16* qrow = Qp + (size_t)(s_base + (sub << 4) + l16) * 64;
        qf[sub][0] = *(const bf16x8*)&qrow[(quad << 3)];
        qf[sub][1] = *(const bf16x8*)&qrow[32 + (quad << 3)];
        for (int j = 0; j < 8; ++j) {     // fold 0.125 * log2(e)
            qf[sub][0][j] = (bf16)((float)qf[sub][0][j] * 0.1803368801f);
            qf[sub][1][j] = (bf16)((float)qf[sub][1][j] * 0.1803368801f);
        }
    }
    bf16x8 ones = {};
    if (l16 == 0) for (int j = 0; j < 8; ++j) ones[j] = (bf16)1.0f;

    f32x4 oacc[2][4] = {};
    f32x4 lacc[2] = {};

    // Clean the vmem scoreboard: Q loads drained; loop vmcnt counts only
    // staging loads (4 per stage call per thread).
    asm volatile("s_waitcnt vmcnt(0)" ::: "memory");

    // prologue: stage tiles 0,1 into buffers 0,1
    attn_stage(Kp, Vp, 0,  (char*)&Ks[0][0], (char*)&Vt[0][0], tid, wave);
    attn_stage(Kp, Vp, 64, (char*)&Ks[1][0], (char*)&Vt[1][0], tid, wave);

    const int NTI = 32;                   // 2048 / 64
    for (int t = 0; t < NTI; ++t) {
        const int buf = t % 3;
        if (t + 2 < NTI) {
            attn_stage(Kp, Vp, (t + 2) << 6,
                       (char*)&Ks[(t + 2) % 3][0], (char*)&Vt[(t + 2) % 3][0],
                       tid, wave);
            asm volatile("s_waitcnt vmcnt(8)" ::: "memory");   // drain tile t
        } else if (t + 1 < NTI) {
            asm volatile("s_waitcnt vmcnt(4)" ::: "memory");   // drain tile t
        } else {
            asm volatile("s_waitcnt vmcnt(0)" ::: "memory");   // last tile
        }
        __builtin_amdgcn_s_barrier();     // all waves' slices resident

        const bf16* Kt_ = &Ks[buf][0];
        const bf16* Vc_ = &Vt[buf][0];

        // QK^T with permuted A-rows; exp2 lands directly in PV fragments.
        bf16x8 pf0[2], pf1[2];
        for (int nt = 0; nt < 4; ++nt) {
            const int g = ((l16 >> 2) << 3) + (l16 & 3)
                        + ((nt & 1) << 2) + ((nt >> 1) << 5);
            const int gs = swz_a(g);
            bf16x8 kf0 = *(const bf16x8*)&Kt_[(g << 6) + ((quad ^ gs) << 3)];
            bf16x8 kf1 = *(const bf16x8*)&Kt_[(g << 6) + (((quad + 4) ^ gs) << 3)];
            __builtin_amdgcn_s_setprio(1);
            for (int sub = 0; sub < 2; ++sub) {
                f32x4 z = {};
                z = MFMA(kf0, qf[sub][0], z);
                z = MFMA(kf1, qf[sub][1], z);
                // slot (quad,r) = P[q=l16][k = 8*quad + 4*(nt&1) + r + 32*(nt>>1)]
                bf16x8& dst = (nt < 2) ? pf0[sub] : pf1[sub];
                const int jb = (nt & 1) << 2;
                for (int r = 0; r < 4; ++r)
                    dst[jb + r] = (bf16)__builtin_amdgcn_exp2f(z[r]);
            }
            __builtin_amdgcn_s_setprio(0);
        }

        __builtin_amdgcn_s_setprio(1);
        for (int ntd = 0; ntd < 4; ++ntd) {
            int row = (ntd << 4) + l16;
            int vs = swz_a(row);
            bf16x8 vf0 = *(const bf16x8*)&Vc_[(row << 6) + ((quad ^ vs) << 3)];
            bf16x8 vf1 = *(const bf16x8*)&Vc_[(row << 6) + (((quad + 4) ^ vs) << 3)];
            for (int sub = 0; sub < 2; ++sub) {
                oacc[sub][ntd] = MFMA(pf0[sub], vf0, oacc[sub][ntd]);
                oacc[sub][ntd] = MFMA(pf1[sub], vf1, oacc[sub][ntd]);
            }
        }
        for (int sub = 0; sub < 2; ++sub) {
            lacc[sub] = MFMA(pf0[sub], ones, lacc[sub]);
            lacc[sub] = MFMA(pf1[sub], ones, lacc[sub]);
        }
        __builtin_amdgcn_s_setprio(0);

        asm volatile("" ::: "memory");
        __builtin_amdgcn_s_barrier();     // all waves done reading buf
    }

    const int b = bh >> 4, h = bh & 15;
    for (int sub = 0; sub < 2; ++sub)
        for (int r = 0; r < 4; ++r) {
            float l = __shfl(lacc[sub][r], quad << 4);   // col-0 lane of quad
            float inv_l = 1.0f / l;
            int srow = s_base + (sub << 4) + (quad << 2) + r;
            for (int ntd = 0; ntd < 4; ++ntd) {
                int d = (ntd << 4) + l16;
                O[((((size_t)b * 2048 + srow) * 16) + h) * 64 + d] =
                    (bf16)(oacc[sub][ntd][r] * inv_l);
            }
        }
}

// ---------------------------------------------------------------------------
// LayerNorm over rows of [8192, 1024]; gamma/beta fp32.
// ---------------------------------------------------------------------------
__global__ __launch_bounds__(256) void layernorm(
    const bf16* __restrict__ x, const float* __restrict__ g,
    const float* __restrict__ b, bf16* __restrict__ y)
{
    __shared__ float red[8];
    const int row = blockIdx.x;
    const int t = threadIdx.x;
    const bf16* xr = x + ((size_t)row << 10);
    bf16x4 xv = *(const bf16x4*)&xr[t << 2];
    float v[4], s = 0.0f, sq = 0.0f;
    for (int i = 0; i < 4; ++i) { v[i] = (float)xv[i]; s += v[i]; sq += v[i] * v[i]; }
    for (int o = 1; o < 64; o <<= 1) { s += __shfl_xor(s, o); sq += __shfl_xor(sq, o); }
    const int wave = t >> 6, lane = t & 63;
    if (lane == 0) { red[wave] = s; red[4 + wave] = sq; }
    __syncthreads();
    s  = red[0] + red[1] + red[2] + red[3];
    sq = red[4] + red[5] + red[6] + red[7];
    float mu = s * (1.0f / 1024.0f);
    float var = fmaxf(sq * (1.0f / 1024.0f) - mu * mu, 0.0f);
    float rstd = rsqrtf(var + 1e-5f);
    bf16x4 ov;
    for (int i = 0; i < 4; ++i) {
        int c = (t << 2) + i;
        ov[i] = (bf16)((v[i] - mu) * rstd * g[c] + b[c]);
    }
    *(bf16x4*)(y + ((size_t)row << 10) + (t << 2)) = ov;
}

// ---------------------------------------------------------------------------
// Orchestration. ws layout (bytes), peak 92 MiB:
//   W2T 0..4M | ln 4..20M (q_bf16 before LN phase) | W1T 20..28M
//   q 28..44M k 44..60M v 60..76M
//   WqkvT 76..82M (dead after QKV gemm) | vt 76..92M (after transpose_v)
//   attn 60..76M (overlay v, dead after transpose_v)
//   h 28..60M [8192][2048] bf16 (overlay q/k after LN consumed attn)
// ---------------------------------------------------------------------------
extern "C" void kernel_launch(void* const* d_in, const int* in_sizes, int n_in,
                              void* d_out, int out_size, void* d_ws, size_t ws_size,
                              hipStream_t stream) {
    (void)in_sizes; (void)n_in; (void)out_size;
    const float* q    = (const float*)d_in[0];
    const float* Wqkv = (const float*)d_in[3];
    const float* bqkv = (const float*)d_in[4];
    const float* qsc  = (const float*)d_in[5];
    const float* ksc  = (const float*)d_in[6];
    const float* lng  = (const float*)d_in[7];
    const float* lnb  = (const float*)d_in[8];
    const float* W1   = (const float*)d_in[9];
    const float* b1   = (const float*)d_in[10];
    const float* W2   = (const float*)d_in[11];
    const float* b2   = (const float*)d_in[12];
    float* out = (float*)d_out;

    const size_t MB = 1024 * 1024;
    if (ws_size < 92 * MB) {
        fill_sentinel<<<8192, 256, 0, stream>>>(out);
        return;
    }

    char* ws = (char*)d_ws;
    bf16* W2T      = (bf16*)(ws + 0);
    bf16* ln_buf   = (bf16*)(ws + 4  * MB);
    bf16* q_bf     = (bf16*)(ws + 4  * MB);  // overlays ln_buf (dead pre-LN)
    bf16* W1T      = (bf16*)(ws + 20 * MB);
    bf16* q_buf    = (bf16*)(ws + 28 * MB);
    bf16* k_buf    = (bf16*)(ws + 44 * MB);
    bf16* v_buf    = (bf16*)(ws + 60 * MB);
    bf16* WqkvT    = (bf16*)(ws + 76 * MB);
    bf16* vt_buf   = (bf16*)(ws + 76 * MB);  // overlays WqkvT (dead post-QKV)
    bf16* attn_buf = (bf16*)(ws + 60 * MB);  // overlays v_buf (dead post-transpose_v)
    bf16* h_buf    = (bf16*)(ws + 28 * MB);  // [8192][2048], overlays q/k

    convert_f32_bf16<<<4096, 256, 0, stream>>>(q, q_bf);
    transpose_f32_bf16<<<512,  256, 0, stream>>>(W2,   W2T,   2048, 1024);
    transpose_f32_bf16<<<1024, 256, 0, stream>>>(W1,   W1T,   1024, 4096);
    transpose_f32_bf16<<<768,  256, 0, stream>>>(Wqkv, WqkvT, 1024, 3072);

    // QKV: [8192,1024] @ [1024,3072] -> scatter q/k/v. BN=128: 32*24=768 (3/CU)
    gemm256<0, 128><<<768, 512, 0, stream>>>(q_bf, WqkvT, bqkv, 8192, 3072, 1024, 1024,
                                             q_buf, k_buf, v_buf, nullptr, nullptr);
    norm_rope<<<65536, 256, 0, stream>>>(q_buf, k_buf, qsc, ksc);
    transpose_v<<<2048, 256, 0, stream>>>(v_buf, vt_buf);
    attn<<<1024, 256, 0, stream>>>(q_buf, k_buf, vt_buf, attn_buf);
    layernorm<<<8192, 256, 0, stream>>>(attn_buf, lng, lnb, ln_buf);
    // FF1 + fused SwiGLU: [8192,1024] @ [1024,4096] -> silu(gate)*x [8192,2048]
    // BN=256 split tiles: 32*16=512 blocks (2/CU)
    gemm256<3, 256><<<512, 512, 0, stream>>>(ln_buf, W1T, b1, 8192, 2048, 1024, 1024,
                                             h_buf, nullptr, nullptr, nullptr, nullptr);
    // FF2: [8192,2048] @ [2048,1024] + resid. BN=128: 32*8=256 (1/CU)
    gemm256<2, 128><<<256, 512, 0, stream>>>(h_buf, W2T, b2, 8192, 1024, 2048, 2048,
                                             nullptr, nullptr, nullptr, out, ln_buf);
}

// Round 8
// 485.997 us; speedup vs baseline: 1.0237x; 1.0237x over previous
//
#include <hip/hip_runtime.h>
#include <math.h>

// Reference is fp32: all d_in are const float*, d_out is float*.
// Internal compute in bf16 (threshold = 2% of |ref|max permits it).
// B=4 S=2048 H=16 DH=64 D=1024; FF_IN=4096 FF_HID=2048.

typedef __bf16 bf16;
typedef bf16 bf16x8 __attribute__((ext_vector_type(8)));
typedef bf16 bf16x4 __attribute__((ext_vector_type(4)));
typedef float f32x4 __attribute__((ext_vector_type(4)));

#define MFMA(a, b, c) __builtin_amdgcn_mfma_f32_16x16x32_bf16(a, b, c, 0, 0, 0)

// Async global->LDS, 16B/lane; LDS dest = wave-uniform base + lane*16.
// XOR-swizzle is applied on the GLOBAL source index so the LDS image is
// swizzled; reads apply the same XOR.
__device__ __forceinline__ void async16(const void* g, void* l) {
    __builtin_amdgcn_global_load_lds(
        (const __attribute__((address_space(1))) void*)g,
        (__attribute__((address_space(3))) void*)l,
        16, 0, 0);
}

// ---------------------------------------------------------------------------
// Diagnostic: fill out with 0.25 if ws_size too small (absmax ~5.31, not NaN).
// ---------------------------------------------------------------------------
__global__ __launch_bounds__(256) void fill_sentinel(float* __restrict__ o)
{
    size_t i = ((size_t)blockIdx.x * 256 + threadIdx.x) * 4;
    *(float4*)&o[i] = make_float4(0.25f, 0.25f, 0.25f, 0.25f);
}

// ---------------------------------------------------------------------------
// fp32 -> bf16 elementwise (for QKV GEMM A operand). 8 elems/thread.
// ---------------------------------------------------------------------------
__global__ __launch_bounds__(256) void convert_f32_bf16(
    const float* __restrict__ in, bf16* __restrict__ out)
{
    size_t i = ((size_t)blockIdx.x * 256 + threadIdx.x) * 8;
    float4 f0 = *(const float4*)&in[i];
    float4 f1 = *(const float4*)&in[i + 4];
    bf16x8 v;
    v[0] = (bf16)f0.x; v[1] = (bf16)f0.y; v[2] = (bf16)f0.z; v[3] = (bf16)f0.w;
    v[4] = (bf16)f1.x; v[5] = (bf16)f1.y; v[6] = (bf16)f1.z; v[7] = (bf16)f1.w;
    *(bf16x8*)&out[i] = v;
}

// ---------------------------------------------------------------------------
// Weight transpose + convert: fp32 [K][N] -> bf16 [N][K], 64x64 tiles.
// ---------------------------------------------------------------------------
__global__ __launch_bounds__(256) void transpose_f32_bf16(
    const float* __restrict__ in, bf16* __restrict__ out, int K, int N)
{
    __shared__ bf16 T[64][70];
    const int tN = N >> 6;
    const int tk = blockIdx.x / tN, tn = blockIdx.x % tN;
    const int k0 = tk << 6, n0 = tn << 6;
    const int t = threadIdx.x;
    const int r = t >> 2, c0 = (t & 3) << 4;
    const float* src = &in[(size_t)(k0 + r) * N + n0 + c0];
    for (int j = 0; j < 4; ++j) {
        float4 f = *(const float4*)(src + 4 * j);
        T[r][c0 + 4 * j + 0] = (bf16)f.x;
        T[r][c0 + 4 * j + 1] = (bf16)f.y;
        T[r][c0 + 4 * j + 2] = (bf16)f.z;
        T[r][c0 + 4 * j + 3] = (bf16)f.w;
    }
    __syncthreads();
    bf16x8 o0, o1;
    for (int i = 0; i < 8; ++i) o0[i] = T[c0 + i][r];
    for (int i = 0; i < 8; ++i) o1[i] = T[c0 + 8 + i][r];
    *(bf16x8*)&out[(size_t)(n0 + r) * K + k0 + c0]     = o0;
    *(bf16x8*)&out[(size_t)(n0 + r) * K + k0 + c0 + 8] = o1;
}

// ---------------------------------------------------------------------------
// 256xBN GEMM, 8 waves (512 thr), BK=64, double-buffered LDS, depth-2
// prefetch with counted vmcnt (never 0 in steady state) and raw s_barrier.
// Chunk XOR-swizzle. Wave grid 2Mx4N. A row stride = lda; BT row stride = K.
// Requires M%256==0, K%128==0, grid%8==0.
//
// EPI 0: scatter qkv. q/k -> C0/C1 as [B,H,S,DH]; V -> C2 DIRECTLY in
//        [bh][d][s] (transposed) layout with packed bf16x4 stores (the 4
//        accumulator rows are 4 consecutive s at fixed d). Deletes the
//        separate transpose_v kernel.
// EPI 1: bf16 C0[row*N+col]
// EPI 2: fp32 Cf[row*N+col] = v + resid (resid bf16)
// EPI 3: FUSED SwiGLU. BN=256; block covers x-cols [n0,n0+128) (B rows
//        0..127 = W1T rows n0+r) and gate-cols [2048+n0,2048+n0+128)
//        (B rows 128..255 = W1T rows n0+1920+r). Wave wn owns x cols
//        wn*32+ni*16+l16 (ni 0,1) and the SAME cols' gates (ni 2,3).
//        Epilogue writes silu(g)*x -> C0 as [M][2048] bf16 (N param = 2048).
// ---------------------------------------------------------------------------
template <int BN, bool SPLIT>
__device__ __forceinline__ void g256_stage(
    const bf16* __restrict__ Ag, const bf16* __restrict__ Bg, int kt,
    int lda, int K, char* aB, char* bB, int tid, int wave)
{
    for (int i = 0; i < 4; ++i) {               // A: 256 rows = 2048 chunks
        int l = (i << 9) + tid;
        int r = l >> 3;
        int cbs = ((l & 7) ^ (r & 7)) << 3;     // swizzled source column
        int cu = (i << 9) + (wave << 6);        // wave-uniform chunk base
        async16(&Ag[(size_t)r * lda + kt + cbs], aB + (size_t)cu * 16);
    }
    for (int i = 0; i < BN / 64; ++i) {         // B: BN rows = BN*8 chunks
        int l = (i << 9) + tid;
        int r = l >> 3;
        int cbs = ((l & 7) ^ (r & 7)) << 3;
        int cu = (i << 9) + (wave << 6);
        size_t grow = SPLIT ? (size_t)(r + ((r >> 7) * 1920)) : (size_t)r;
        async16(&Bg[grow * K + kt + cbs], bB + (size_t)cu * 16);
    }
}

template <int NI, bool SPLIT>
__device__ __forceinline__ void g256_compute(
    const bf16* At, const bf16* Bt, f32x4 (&acc)[8][NI],
    int wm, int wn, int l16, int quad, int rsw)
{
    for (int kd = 0; kd < 2; ++kd) {
        bf16x8 af[8], bfr[NI];
        for (int mi = 0; mi < 8; ++mi) {
            int row = (wm << 7) + (mi << 4) + l16;
            af[mi] = *(const bf16x8*)&At[(row << 6) + ((((kd << 2) + quad) ^ rsw) << 3)];
        }
        for (int ni = 0; ni < NI; ++ni) {
            int row;
            if (SPLIT)   // ni 0,1 = x rows [0,128); ni 2,3 = gate rows [128,256)
                row = ((ni >= 2) ? 128 : 0) + (wn << 5) + ((ni & 1) << 4) + l16;
            else
                row = wn * (NI << 4) + (ni << 4) + l16;
            bfr[ni] = *(const bf16x8*)&Bt[(row << 6) + ((((kd << 2) + quad) ^ rsw) << 3)];
        }
        __builtin_amdgcn_s_setprio(1);
        for (int mi = 0; mi < 8; ++mi)
            for (int ni = 0; ni < NI; ++ni)
                acc[mi][ni] = MFMA(af[mi], bfr[ni], acc[mi][ni]);
        __builtin_amdgcn_s_setprio(0);
    }
}

#define G256_WAIT()                                                        \
    if constexpr (BN == 256) asm volatile("s_waitcnt vmcnt(8)" ::: "memory"); \
    else                     asm volatile("s_waitcnt vmcnt(6)" ::: "memory")

template <int EPI, int BN>
__global__ __launch_bounds__(512, 2) void gemm256(
    const bf16* __restrict__ A, const bf16* __restrict__ BT,
    const float* __restrict__ bias, int M, int N, int K, int lda,
    bf16* __restrict__ C0, bf16* __restrict__ C1, bf16* __restrict__ C2,
    float* __restrict__ Cf, const bf16* __restrict__ resid)
{
    constexpr int NI = BN / 64;                 // ni count per wave
    constexpr bool SPLIT = (EPI == 3);
    constexpr int TILE_N = SPLIT ? 128 : BN;    // output cols per block
    __shared__ bf16 As[2][256 * 64];
    __shared__ bf16 Bs[2][BN * 64];
    const int tid = threadIdx.x;
    const int lane = tid & 63, wave = tid >> 6;
    const int quad = lane >> 4, l16 = lane & 15;
    const int rsw = l16 & 7;
    const int wm = wave >> 2, wn = wave & 3;    // 2 x 4 wave grid
    const int nb = N / TILE_N;
    const int nwg = gridDim.x;                  // grid % 8 == 0 (caller)
    const int bid = blockIdx.x;
    const int swz = (bid & 7) * (nwg >> 3) + (bid >> 3);   // XCD-chunked
    const int bm = swz / nb, bn = swz % nb;
    const int m0 = bm << 8, n0 = bn * TILE_N;
    const bf16* Ag = A + (size_t)m0 * lda;
    const bf16* Bg = BT + (size_t)n0 * K;
    char* a0 = (char*)&As[0][0]; char* a1 = (char*)&As[1][0];
    char* b0 = (char*)&Bs[0][0]; char* b1 = (char*)&Bs[1][0];

    f32x4 acc[8][NI] = {};
    const int NT = K >> 6;                      // even (K%128==0)

    g256_stage<BN, SPLIT>(Ag, Bg, 0,  lda, K, a0, b0, tid, wave);
    g256_stage<BN, SPLIT>(Ag, Bg, 64, lda, K, a1, b1, tid, wave);
    G256_WAIT();                                // tile 0 resident
    __builtin_amdgcn_s_barrier();

    for (int t = 0; t < NT; t += 2) {
        // even tile -> buf 0
        g256_compute<NI, SPLIT>(&As[0][0], &Bs[0][0], acc, wm, wn, l16, quad, rsw);
        asm volatile("" ::: "memory");
        __builtin_amdgcn_s_barrier();
        if (t + 2 < NT) {
            g256_stage<BN, SPLIT>(Ag, Bg, (t + 2) << 6, lda, K, a0, b0, tid, wave);
            G256_WAIT();
        } else {
            asm volatile("s_waitcnt vmcnt(0)" ::: "memory");
        }
        __builtin_amdgcn_s_barrier();
        // odd tile -> buf 1
        g256_compute<NI, SPLIT>(&As[1][0], &Bs[1][0], acc, wm, wn, l16, quad, rsw);
        asm volatile("" ::: "memory");
        __builtin_amdgcn_s_barrier();
        if (t + 3 < NT) {
            g256_stage<BN, SPLIT>(Ag, Bg, (t + 3) << 6, lda, K, a1, b1, tid, wave);
            G256_WAIT();
        } else {
            asm volatile("s_waitcnt vmcnt(0)" ::: "memory");
        }
        __builtin_amdgcn_s_barrier();
    }

    if (EPI == 3) {
        for (int mi = 0; mi < 8; ++mi) {
            for (int ni = 0; ni < 2; ++ni) {
                for (int r = 0; r < 4; ++r) {
                    int row  = m0 + (wm << 7) + (mi << 4) + (quad << 2) + r;
                    int colx = n0 + (wn << 5) + (ni << 4) + l16;
                    float x = acc[mi][ni][r]     + bias[colx];
                    float g = acc[mi][ni + 2][r] + bias[2048 + colx];
                    float s = g / (1.0f + __expf(-g)) * x;
                    C0[(size_t)row * N + colx] = (bf16)s;
                }
            }
        }
        return;
    }

    if (EPI == 0) {
        for (int mi = 0; mi < 8; ++mi) {
            for (int ni = 0; ni < NI; ++ni) {
                int row0 = m0 + (wm << 7) + (mi << 4) + (quad << 2);
                int col  = n0 + wn * (NI << 4) + (ni << 4) + l16;
                int b  = row0 >> 11, s0 = row0 & 2047;
                int h  = col / 192, w = col % 192;
                int tq = w >> 6, d = w & 63;
                int bh = b * 16 + h;
                float bia = bias[col];
                if (tq == 2) {                 // V: [bh][d][s], packed 4 s
                    bf16x4 pk;
                    for (int r = 0; r < 4; ++r)
                        pk[r] = (bf16)(acc[mi][ni][r] + bia);
                    *(bf16x4*)&C2[((size_t)bh << 17) + (size_t)d * 2048 + s0] = pk;
                } else {                        // q/k: [bh][s][d] scalar
                    bf16* dst = (tq == 0) ? C0 : C1;
                    for (int r = 0; r < 4; ++r)
                        dst[(((size_t)bh * 2048 + s0 + r) << 6) + d] =
                            (bf16)(acc[mi][ni][r] + bia);
                }
            }
        }
        return;
    }

    for (int mi = 0; mi < 8; ++mi) {
        for (int ni = 0; ni < NI; ++ni) {
            for (int r = 0; r < 4; ++r) {
                int row = m0 + (wm << 7) + (mi << 4) + (quad << 2) + r;
                int col = n0 + wn * (NI << 4) + (ni << 4) + l16;
                float v = acc[mi][ni][r] + bias[col];
                if (EPI == 1) {
                    C0[(size_t)row * N + col] = (bf16)v;
                } else {
                    float rv = (float)resid[(size_t)row * N + col];
                    Cf[(size_t)row * N + col] = v + rv;
                }
            }
        }
    }
}

// ---------------------------------------------------------------------------
// Fused l2norm + head-scale + xpos RoPE, in place, HW transcendentals.
// ---------------------------------------------------------------------------
__global__ __launch_bounds__(256) void norm_rope(
    bf16* __restrict__ qb, bf16* __restrict__ kb,
    const float* __restrict__ qs, const float* __restrict__ ks)
{
    const int wave = threadIdx.x >> 6, lane = threadIdx.x & 63;
    const int rid = blockIdx.x * 4 + wave;          // 0 .. 262143
    const bool is_k = rid >= 131072;
    const int idx = is_k ? rid - 131072 : rid;      // bh*2048 + s
    const int s = idx & 2047;
    bf16* ptr = (is_k ? kb : qb) + ((size_t)idx << 6);
    const int d = lane;

    float v = (float)ptr[d];
    float ss = v * v;
    for (int o = 1; o < 64; o <<= 1) ss += __shfl_xor(ss, o);
    float t = v * rsqrtf(fmaxf(ss, 1e-24f));
    t *= (is_k ? ks : qs)[d];

    float partner = __shfl_xor(t, 32);
    float rh = (d < 32) ? -partner : partner;       // rotate_half

    const float fi = (float)(d & 31);
    float inv_freq = __builtin_amdgcn_exp2f(fi * -0.4152410118609203f);
    float pos = (float)s * inv_freq;
    float rev = pos * 0.15915494309189535f;         // v_sin takes revolutions
    rev = rev - floorf(rev);
    float sn = __builtin_amdgcn_sinf(rev);
    float cs = __builtin_amdgcn_cosf(rev);
    float base = (2.0f * fi + 25.6f) * (1.0f / 89.6f);
    float power = ((float)s - 1024.0f) * (1.0f / 512.0f);
    if (is_k) power = -power;
    float xsc = __builtin_amdgcn_exp2f(power * __builtin_amdgcn_logf(base));
    ptr[d] = (bf16)((t * cs + rh * sn) * xsc);
}

// ---------------------------------------------------------------------------
// Flash attention, no-max softmax (|score|/8 <= ~19 -> exp <= 1.4e8, fp32-safe;
// 0.125*log2e folded into Q; P = exp2). Row-sums via ones-column MFMA.
//
// ZERO-MOVEMENT P (R4): permuted Ks rows make the swapped-QK^T output land
// exactly in the PV A-fragment; exp2 feeds MFMA operands directly.
// bh-clustered XCD remap (R6): K/V L2-resident per XCD.
// R6 loop structure (R7's counted-vmcnt regressed -> reverted).
//
// R8: QBLK 128 -> 64. R5-R7 showed attn pinned at ~100us with MfmaUtil ~30,
// VALUBusy ~44, occupancy ~24% invariant -> dependency-chain-bound with too
// little TLP. Halving the Q-block doubles the grid (2048 blocks, 8/CU work,
// 5 resident by LDS=32KB) and 2.5x's the independent wave count per CU.
// Each wave owns 16 q-rows (1 subtile). K/V staged 2x more often (FETCH
// ~25 -> ~49MB, still ~5% HBM, L2-resident).
// ---------------------------------------------------------------------------
__device__ __forceinline__ int swz_a(int r) {
    int a = (r >> 3) & 3;
    return (r & 7) ^ a ^ ((a << 1) & 7);
}

__device__ __forceinline__ void attn_stage(
    const bf16* __restrict__ Kp, const bf16* __restrict__ Vp, int kt,
    char* kB, char* vB, int tid, int wave)
{
    for (int i = 0; i < 2; ++i) {
        int l = (i << 8) + tid;
        int r = l >> 3;
        int cbs = ((l & 7) ^ swz_a(r)) << 3;
        int cu = (i << 8) + (wave << 6);
        async16(&Kp[(size_t)(kt + r) * 64 + cbs], kB + (size_t)cu * 16);
        async16(&Vp[(size_t)r * 2048 + kt + cbs], vB + (size_t)cu * 16);
    }
}

__global__ __launch_bounds__(256) void attn(
    const bf16* __restrict__ Q, const bf16* __restrict__ Kb,
    const bf16* __restrict__ VT, bf16* __restrict__ O)
{
    __shared__ bf16 Ks[2][64 * 64];
    __shared__ bf16 Vt[2][64 * 64];       // Vt[d][j] image (swizzled chunks)
    const int tid = threadIdx.x;
    const int lane = tid & 63, wave = tid >> 6;
    const int quad = lane >> 4, l16 = lane & 15;
    const int wgi = blockIdx.x;           // 2048 blocks
    const int rr = wgi >> 3;              // 0..255
    const int bh = ((wgi & 7) << 3) + (rr >> 5);   // bh-clustered per XCD
    const int q0 = (rr & 31) << 6;
    const int s_base = q0 + (wave << 4);  // wave owns 16 q-rows
    const bf16* Qp = Q + ((size_t)bh << 17);
    const bf16* Kp = Kb + ((size_t)bh << 17);
    const bf16* Vp = VT + ((size_t)bh << 17);

    bf16x8 qf[2];
    {
        const bf16* qrow = Qp + (size_t)(s_base + l16) * 64;
        qf[0] = *(const bf16x8*)&qrow[(quad << 3)];
        qf[1] = *(const bf16x8*)&qrow[32 + (quad << 3)];
        for (int j = 0; j < 8; ++j) {     // fold 0.125 * log2(e)
            qf[0][j] = (bf16)((float)qf[0][j] * 0.1803368801f);
            qf[1][j] = (bf16)((float)qf[1][j] * 0.1803368801f);
        }
    }
    bf16x8 ones = {};
    if (l16 == 0) for (int j = 0; j < 8; ++j) ones[j] = (bf16)1.0f;

    f32x4 oacc[4] = {};
    f32x4 lacc = {};

    // prologue: stage tile 0 into buffer 0
    attn_stage(Kp, Vp, 0, (char*)&Ks[0][0], (char*)&Vt[0][0], tid, wave);

    int buf = 0;
    for (int kt = 0; kt < 2048; kt += 64, buf ^= 1) {
        // barrier: drains vmcnt -> tile kt resident in buf; all waves are
        // also done reading buf^1 (prev iteration's compute precedes this
        // barrier in program order) so it is safe to overwrite.
        __syncthreads();
        if (kt + 64 < 2048)
            attn_stage(Kp, Vp, kt + 64,
                       (char*)&Ks[buf ^ 1][0], (char*)&Vt[buf ^ 1][0], tid, wave);

        const bf16* Kt_ = &Ks[buf][0];
        const bf16* Vc_ = &Vt[buf][0];

        // QK^T with permuted A-rows; exp2 lands directly in PV fragments.
        bf16x8 pf0, pf1;
        for (int nt = 0; nt < 4; ++nt) {
            const int g = ((l16 >> 2) << 3) + (l16 & 3)
                        + ((nt & 1) << 2) + ((nt >> 1) << 5);
            const int gs = swz_a(g);
            bf16x8 kf0 = *(const bf16x8*)&Kt_[(g << 6) + ((quad ^ gs) << 3)];
            bf16x8 kf1 = *(const bf16x8*)&Kt_[(g << 6) + (((quad + 4) ^ gs) << 3)];
            __builtin_amdgcn_s_setprio(1);
            f32x4 z = {};
            z = MFMA(kf0, qf[0], z);
            z = MFMA(kf1, qf[1], z);
            __builtin_amdgcn_s_setprio(0);
            // slot (quad,r) = P[q=l16][k = 8*quad + 4*(nt&1) + r + 32*(nt>>1)]
            bf16x8& dst = (nt < 2) ? pf0 : pf1;
            const int jb = (nt & 1) << 2;
            for (int r = 0; r < 4; ++r)
                dst[jb + r] = (bf16)__builtin_amdgcn_exp2f(z[r]);
        }

        __builtin_amdgcn_s_setprio(1);
        for (int ntd = 0; ntd < 4; ++ntd) {
            int row = (ntd << 4) + l16;
            int vs = swz_a(row);
            bf16x8 vf0 = *(const bf16x8*)&Vc_[(row << 6) + ((quad ^ vs) << 3)];
            bf16x8 vf1 = *(const bf16x8*)&Vc_[(row << 6) + (((quad + 4) ^ vs) << 3)];
            oacc[ntd] = MFMA(pf0, vf0, oacc[ntd]);
            oacc[ntd] = MFMA(pf1, vf1, oacc[ntd]);
        }
        lacc = MFMA(pf0, ones, lacc);
        lacc = MFMA(pf1, ones, lacc);
        __builtin_amdgcn_s_setprio(0);
    }

    const int b = bh >> 4, h = bh & 15;
    for (int r = 0; r < 4; ++r) {
        float l = __shfl(lacc[r], quad << 4);   // col-0 lane of quad
        float inv_l = 1.0f / l;
        int srow = s_base + (quad << 2) + r;
        for (int ntd = 0; ntd < 4; ++ntd) {
            int d = (ntd << 4) + l16;
            O[((((size_t)b * 2048 + srow) * 16) + h) * 64 + d] =
                (bf16)(oacc[ntd][r] * inv_l);
        }
    }
}

// ---------------------------------------------------------------------------
// LayerNorm over rows of [8192, 1024]; gamma/beta fp32.
// ---------------------------------------------------------------------------
__global__ __launch_bounds__(256) void layernorm(
    const bf16* __restrict__ x, const float* __restrict__ g,
    const float* __restrict__ b, bf16* __restrict__ y)
{
    __shared__ float red[8];
    const int row = blockIdx.x;
    const int t = threadIdx.x;
    const bf16* xr = x + ((size_t)row << 10);
    bf16x4 xv = *(const bf16x4*)&xr[t << 2];
    float v[4], s = 0.0f, sq = 0.0f;
    for (int i = 0; i < 4; ++i) { v[i] = (float)xv[i]; s += v[i]; sq += v[i] * v[i]; }
    for (int o = 1; o < 64; o <<= 1) { s += __shfl_xor(s, o); sq += __shfl_xor(sq, o); }
    const int wave = t >> 6, lane = t & 63;
    if (lane == 0) { red[wave] = s; red[4 + wave] = sq; }
    __syncthreads();
    s  = red[0] + red[1] + red[2] + red[3];
    sq = red[4] + red[5] + red[6] + red[7];
    float mu = s * (1.0f / 1024.0f);
    float var = fmaxf(sq * (1.0f / 1024.0f) - mu * mu, 0.0f);
    float rstd = rsqrtf(var + 1e-5f);
    bf16x4 ov;
    for (int i = 0; i < 4; ++i) {
        int c = (t << 2) + i;
        ov[i] = (bf16)((v[i] - mu) * rstd * g[c] + b[c]);
    }
    *(bf16x4*)(y + ((size_t)row << 10) + (t << 2)) = ov;
}

// ---------------------------------------------------------------------------
// Orchestration. ws layout (bytes), peak 92 MiB:
//   W2T 0..4M | ln 4..20M (q_bf16 before LN phase) | W1T 20..28M
//   q 28..44M k 44..60M vt 60..76M
//   WqkvT 76..82M (dead after QKV gemm) | attn 76..92M (overlay WqkvT)
//   h 28..60M [8192][2048] bf16 (overlay q/k after LN consumed attn)
// ---------------------------------------------------------------------------
extern "C" void kernel_launch(void* const* d_in, const int* in_sizes, int n_in,
                              void* d_out, int out_size, void* d_ws, size_t ws_size,
                              hipStream_t stream) {
    (void)in_sizes; (void)n_in; (void)out_size;
    const float* q    = (const float*)d_in[0];
    const float* Wqkv = (const float*)d_in[3];
    const float* bqkv = (const float*)d_in[4];
    const float* qsc  = (const float*)d_in[5];
    const float* ksc  = (const float*)d_in[6];
    const float* lng  = (const float*)d_in[7];
    const float* lnb  = (const float*)d_in[8];
    const float* W1   = (const float*)d_in[9];
    const float* b1   = (const float*)d_in[10];
    const float* W2   = (const float*)d_in[11];
    const float* b2   = (const float*)d_in[12];
    float* out = (float*)d_out;

    const size_t MB = 1024 * 1024;
    if (ws_size < 92 * MB) {
        fill_sentinel<<<8192, 256, 0, stream>>>(out);
        return;
    }

    char* ws = (char*)d_ws;
    bf16* W2T      = (bf16*)(ws + 0);
    bf16* ln_buf   = (bf16*)(ws + 4  * MB);
    bf16* q_bf     = (bf16*)(ws + 4  * MB);  // overlays ln_buf (dead pre-LN)
    bf16* W1T      = (bf16*)(ws + 20 * MB);
    bf16* q_buf    = (bf16*)(ws + 28 * MB);
    bf16* k_buf    = (bf16*)(ws + 44 * MB);
    bf16* vt_buf   = (bf16*)(ws + 60 * MB);  // V written transposed by QKV gemm
    bf16* WqkvT    = (bf16*)(ws + 76 * MB);
    bf16* attn_buf = (bf16*)(ws + 76 * MB);  // overlays WqkvT (dead post-QKV)
    bf16* h_buf    = (bf16*)(ws + 28 * MB);  // [8192][2048], overlays q/k

    convert_f32_bf16<<<4096, 256, 0, stream>>>(q, q_bf);
    transpose_f32_bf16<<<512,  256, 0, stream>>>(W2,   W2T,   2048, 1024);
    transpose_f32_bf16<<<1024, 256, 0, stream>>>(W1,   W1T,   1024, 4096);
    transpose_f32_bf16<<<768,  256, 0, stream>>>(Wqkv, WqkvT, 1024, 3072);

    // QKV: [8192,1024] @ [1024,3072] -> scatter q/k + V transposed.
    // BN=128: 32*24=768 (3/CU)
    gemm256<0, 128><<<768, 512, 0, stream>>>(q_bf, WqkvT, bqkv, 8192, 3072, 1024, 1024,
                                             q_buf, k_buf, vt_buf, nullptr, nullptr);
    norm_rope<<<65536, 256, 0, stream>>>(q_buf, k_buf, qsc, ksc);
    attn<<<2048, 256, 0, stream>>>(q_buf, k_buf, vt_buf, attn_buf);
    layernorm<<<8192, 256, 0, stream>>>(attn_buf, lng, lnb, ln_buf);
    // FF1 + fused SwiGLU: [8192,1024] @ [1024,4096] -> silu(gate)*x [8192,2048]
    // BN=256 split tiles: 32*16=512 blocks (2/CU)
    gemm256<3, 256><<<512, 512, 0, stream>>>(ln_buf, W1T, b1, 8192, 2048, 1024, 1024,
                                             h_buf, nullptr, nullptr, nullptr, nullptr);
    // FF2: [8192,2048] @ [2048,1024] + resid. BN=128: 32*8=256 (1/CU)
    gemm256<2, 128><<<256, 512, 0, stream>>>(h_buf, W2T, b2, 8192, 1024, 2048, 2048,
                                             nullptr, nullptr, nullptr, out, ln_buf);
}

// Round 9
// 479.670 us; speedup vs baseline: 1.0372x; 1.0132x over previous
//
#include <hip/hip_runtime.h>
#include <math.h>

// Reference is fp32: all d_in are const float*, d_out is float*.
// Internal compute in bf16 (threshold = 2% of |ref|max permits it).
// B=4 S=2048 H=16 DH=64 D=1024; FF_IN=4096 FF_HID=2048.

typedef __bf16 bf16;
typedef bf16 bf16x8 __attribute__((ext_vector_type(8)));
typedef bf16 bf16x4 __attribute__((ext_vector_type(4)));
typedef float f32x4 __attribute__((ext_vector_type(4)));

#define MFMA(a, b, c) __builtin_amdgcn_mfma_f32_16x16x32_bf16(a, b, c, 0, 0, 0)

// Async global->LDS, 16B/lane; LDS dest = wave-uniform base + lane*16.
// XOR-swizzle is applied on the GLOBAL source index so the LDS image is
// swizzled; reads apply the same XOR.
__device__ __forceinline__ void async16(const void* g, void* l) {
    __builtin_amdgcn_global_load_lds(
        (const __attribute__((address_space(1))) void*)g,
        (__attribute__((address_space(3))) void*)l,
        16, 0, 0);
}

// ---------------------------------------------------------------------------
// Diagnostic: fill out with 0.25 if ws_size too small (absmax ~5.31, not NaN).
// ---------------------------------------------------------------------------
__global__ __launch_bounds__(256) void fill_sentinel(float* __restrict__ o)
{
    size_t i = ((size_t)blockIdx.x * 256 + threadIdx.x) * 4;
    *(float4*)&o[i] = make_float4(0.25f, 0.25f, 0.25f, 0.25f);
}

// ---------------------------------------------------------------------------
// fp32 -> bf16 elementwise (for QKV GEMM A operand). 8 elems/thread.
// ---------------------------------------------------------------------------
__global__ __launch_bounds__(256) void convert_f32_bf16(
    const float* __restrict__ in, bf16* __restrict__ out)
{
    size_t i = ((size_t)blockIdx.x * 256 + threadIdx.x) * 8;
    float4 f0 = *(const float4*)&in[i];
    float4 f1 = *(const float4*)&in[i + 4];
    bf16x8 v;
    v[0] = (bf16)f0.x; v[1] = (bf16)f0.y; v[2] = (bf16)f0.z; v[3] = (bf16)f0.w;
    v[4] = (bf16)f1.x; v[5] = (bf16)f1.y; v[6] = (bf16)f1.z; v[7] = (bf16)f1.w;
    *(bf16x8*)&out[i] = v;
}

// ---------------------------------------------------------------------------
// Weight transpose + convert: fp32 [K][N] -> bf16 [N][K], 64x64 tiles.
// ---------------------------------------------------------------------------
__global__ __launch_bounds__(256) void transpose_f32_bf16(
    const float* __restrict__ in, bf16* __restrict__ out, int K, int N)
{
    __shared__ bf16 T[64][70];
    const int tN = N >> 6;
    const int tk = blockIdx.x / tN, tn = blockIdx.x % tN;
    const int k0 = tk << 6, n0 = tn << 6;
    const int t = threadIdx.x;
    const int r = t >> 2, c0 = (t & 3) << 4;
    const float* src = &in[(size_t)(k0 + r) * N + n0 + c0];
    for (int j = 0; j < 4; ++j) {
        float4 f = *(const float4*)(src + 4 * j);
        T[r][c0 + 4 * j + 0] = (bf16)f.x;
        T[r][c0 + 4 * j + 1] = (bf16)f.y;
        T[r][c0 + 4 * j + 2] = (bf16)f.z;
        T[r][c0 + 4 * j + 3] = (bf16)f.w;
    }
    __syncthreads();
    bf16x8 o0, o1;
    for (int i = 0; i < 8; ++i) o0[i] = T[c0 + i][r];
    for (int i = 0; i < 8; ++i) o1[i] = T[c0 + 8 + i][r];
    *(bf16x8*)&out[(size_t)(n0 + r) * K + k0 + c0]     = o0;
    *(bf16x8*)&out[(size_t)(n0 + r) * K + k0 + c0 + 8] = o1;
}

// ---------------------------------------------------------------------------
// 256xBN GEMM, 8 waves (512 thr), BK=64, double-buffered LDS, depth-2
// prefetch with counted vmcnt (never 0 in steady state) and raw s_barrier.
// Chunk XOR-swizzle. Wave grid 2Mx4N. A row stride = lda; BT row stride = K.
// Requires M%256==0, K%128==0, grid%8==0.
//
// EPI 0: scatter qkv. q/k -> C0/C1 as [B,H,S,DH]; V -> C2 DIRECTLY in
//        [bh][d][s] (transposed) layout with packed bf16x4 stores.
// EPI 1: bf16 C0[row*N+col]
// EPI 2: fp32 Cf[row*N+col] = v + resid (resid bf16)
// EPI 3: FUSED SwiGLU (BN=256 split tiles, writes [M][2048] bf16).
// ---------------------------------------------------------------------------
template <int BN, bool SPLIT>
__device__ __forceinline__ void g256_stage(
    const bf16* __restrict__ Ag, const bf16* __restrict__ Bg, int kt,
    int lda, int K, char* aB, char* bB, int tid, int wave)
{
    for (int i = 0; i < 4; ++i) {               // A: 256 rows = 2048 chunks
        int l = (i << 9) + tid;
        int r = l >> 3;
        int cbs = ((l & 7) ^ (r & 7)) << 3;     // swizzled source column
        int cu = (i << 9) + (wave << 6);        // wave-uniform chunk base
        async16(&Ag[(size_t)r * lda + kt + cbs], aB + (size_t)cu * 16);
    }
    for (int i = 0; i < BN / 64; ++i) {         // B: BN rows = BN*8 chunks
        int l = (i << 9) + tid;
        int r = l >> 3;
        int cbs = ((l & 7) ^ (r & 7)) << 3;
        int cu = (i << 9) + (wave << 6);
        size_t grow = SPLIT ? (size_t)(r + ((r >> 7) * 1920)) : (size_t)r;
        async16(&Bg[grow * K + kt + cbs], bB + (size_t)cu * 16);
    }
}

template <int NI, bool SPLIT>
__device__ __forceinline__ void g256_compute(
    const bf16* At, const bf16* Bt, f32x4 (&acc)[8][NI],
    int wm, int wn, int l16, int quad, int rsw)
{
    for (int kd = 0; kd < 2; ++kd) {
        bf16x8 af[8], bfr[NI];
        for (int mi = 0; mi < 8; ++mi) {
            int row = (wm << 7) + (mi << 4) + l16;
            af[mi] = *(const bf16x8*)&At[(row << 6) + ((((kd << 2) + quad) ^ rsw) << 3)];
        }
        for (int ni = 0; ni < NI; ++ni) {
            int row;
            if (SPLIT)   // ni 0,1 = x rows [0,128); ni 2,3 = gate rows [128,256)
                row = ((ni >= 2) ? 128 : 0) + (wn << 5) + ((ni & 1) << 4) + l16;
            else
                row = wn * (NI << 4) + (ni << 4) + l16;
            bfr[ni] = *(const bf16x8*)&Bt[(row << 6) + ((((kd << 2) + quad) ^ rsw) << 3)];
        }
        __builtin_amdgcn_s_setprio(1);
        for (int mi = 0; mi < 8; ++mi)
            for (int ni = 0; ni < NI; ++ni)
                acc[mi][ni] = MFMA(af[mi], bfr[ni], acc[mi][ni]);
        __builtin_amdgcn_s_setprio(0);
    }
}

#define G256_WAIT()                                                        \
    if constexpr (BN == 256) asm volatile("s_waitcnt vmcnt(8)" ::: "memory"); \
    else                     asm volatile("s_waitcnt vmcnt(6)" ::: "memory")

template <int EPI, int BN>
__global__ __launch_bounds__(512, 2) void gemm256(
    const bf16* __restrict__ A, const bf16* __restrict__ BT,
    const float* __restrict__ bias, int M, int N, int K, int lda,
    bf16* __restrict__ C0, bf16* __restrict__ C1, bf16* __restrict__ C2,
    float* __restrict__ Cf, const bf16* __restrict__ resid)
{
    constexpr int NI = BN / 64;                 // ni count per wave
    constexpr bool SPLIT = (EPI == 3);
    constexpr int TILE_N = SPLIT ? 128 : BN;    // output cols per block
    __shared__ bf16 As[2][256 * 64];
    __shared__ bf16 Bs[2][BN * 64];
    const int tid = threadIdx.x;
    const int lane = tid & 63, wave = tid >> 6;
    const int quad = lane >> 4, l16 = lane & 15;
    const int rsw = l16 & 7;
    const int wm = wave >> 2, wn = wave & 3;    // 2 x 4 wave grid
    const int nb = N / TILE_N;
    const int nwg = gridDim.x;                  // grid % 8 == 0 (caller)
    const int bid = blockIdx.x;
    const int swz = (bid & 7) * (nwg >> 3) + (bid >> 3);   // XCD-chunked
    const int bm = swz / nb, bn = swz % nb;
    const int m0 = bm << 8, n0 = bn * TILE_N;
    const bf16* Ag = A + (size_t)m0 * lda;
    const bf16* Bg = BT + (size_t)n0 * K;
    char* a0 = (char*)&As[0][0]; char* a1 = (char*)&As[1][0];
    char* b0 = (char*)&Bs[0][0]; char* b1 = (char*)&Bs[1][0];

    f32x4 acc[8][NI] = {};
    const int NT = K >> 6;                      // even (K%128==0)

    g256_stage<BN, SPLIT>(Ag, Bg, 0,  lda, K, a0, b0, tid, wave);
    g256_stage<BN, SPLIT>(Ag, Bg, 64, lda, K, a1, b1, tid, wave);
    G256_WAIT();                                // tile 0 resident
    __builtin_amdgcn_s_barrier();

    for (int t = 0; t < NT; t += 2) {
        // even tile -> buf 0
        g256_compute<NI, SPLIT>(&As[0][0], &Bs[0][0], acc, wm, wn, l16, quad, rsw);
        asm volatile("" ::: "memory");
        __builtin_amdgcn_s_barrier();
        if (t + 2 < NT) {
            g256_stage<BN, SPLIT>(Ag, Bg, (t + 2) << 6, lda, K, a0, b0, tid, wave);
            G256_WAIT();
        } else {
            asm volatile("s_waitcnt vmcnt(0)" ::: "memory");
        }
        __builtin_amdgcn_s_barrier();
        // odd tile -> buf 1
        g256_compute<NI, SPLIT>(&As[1][0], &Bs[1][0], acc, wm, wn, l16, quad, rsw);
        asm volatile("" ::: "memory");
        __builtin_amdgcn_s_barrier();
        if (t + 3 < NT) {
            g256_stage<BN, SPLIT>(Ag, Bg, (t + 3) << 6, lda, K, a1, b1, tid, wave);
            G256_WAIT();
        } else {
            asm volatile("s_waitcnt vmcnt(0)" ::: "memory");
        }
        __builtin_amdgcn_s_barrier();
    }

    if (EPI == 3) {
        for (int mi = 0; mi < 8; ++mi) {
            for (int ni = 0; ni < 2; ++ni) {
                for (int r = 0; r < 4; ++r) {
                    int row  = m0 + (wm << 7) + (mi << 4) + (quad << 2) + r;
                    int colx = n0 + (wn << 5) + (ni << 4) + l16;
                    float x = acc[mi][ni][r]     + bias[colx];
                    float g = acc[mi][ni + 2][r] + bias[2048 + colx];
                    float s = g / (1.0f + __expf(-g)) * x;
                    C0[(size_t)row * N + colx] = (bf16)s;
                }
            }
        }
        return;
    }

    if (EPI == 0) {
        for (int mi = 0; mi < 8; ++mi) {
            for (int ni = 0; ni < NI; ++ni) {
                int row0 = m0 + (wm << 7) + (mi << 4) + (quad << 2);
                int col  = n0 + wn * (NI << 4) + (ni << 4) + l16;
                int b  = row0 >> 11, s0 = row0 & 2047;
                int h  = col / 192, w = col % 192;
                int tq = w >> 6, d = w & 63;
                int bh = b * 16 + h;
                float bia = bias[col];
                if (tq == 2) {                 // V: [bh][d][s], packed 4 s
                    bf16x4 pk;
                    for (int r = 0; r < 4; ++r)
                        pk[r] = (bf16)(acc[mi][ni][r] + bia);
                    *(bf16x4*)&C2[((size_t)bh << 17) + (size_t)d * 2048 + s0] = pk;
                } else {                        // q/k: [bh][s][d] scalar
                    bf16* dst = (tq == 0) ? C0 : C1;
                    for (int r = 0; r < 4; ++r)
                        dst[(((size_t)bh * 2048 + s0 + r) << 6) + d] =
                            (bf16)(acc[mi][ni][r] + bia);
                }
            }
        }
        return;
    }

    for (int mi = 0; mi < 8; ++mi) {
        for (int ni = 0; ni < NI; ++ni) {
            for (int r = 0; r < 4; ++r) {
                int row = m0 + (wm << 7) + (mi << 4) + (quad << 2) + r;
                int col = n0 + wn * (NI << 4) + (ni << 4) + l16;
                float v = acc[mi][ni][r] + bias[col];
                if (EPI == 1) {
                    C0[(size_t)row * N + col] = (bf16)v;
                } else {
                    float rv = (float)resid[(size_t)row * N + col];
                    Cf[(size_t)row * N + col] = v + rv;
                }
            }
        }
    }
}

// ---------------------------------------------------------------------------
// Fused l2norm + head-scale + xpos RoPE, in place, HW transcendentals.
// ---------------------------------------------------------------------------
__global__ __launch_bounds__(256) void norm_rope(
    bf16* __restrict__ qb, bf16* __restrict__ kb,
    const float* __restrict__ qs, const float* __restrict__ ks)
{
    const int wave = threadIdx.x >> 6, lane = threadIdx.x & 63;
    const int rid = blockIdx.x * 4 + wave;          // 0 .. 262143
    const bool is_k = rid >= 131072;
    const int idx = is_k ? rid - 131072 : rid;      // bh*2048 + s
    const int s = idx & 2047;
    bf16* ptr = (is_k ? kb : qb) + ((size_t)idx << 6);
    const int d = lane;

    float v = (float)ptr[d];
    float ss = v * v;
    for (int o = 1; o < 64; o <<= 1) ss += __shfl_xor(ss, o);
    float t = v * rsqrtf(fmaxf(ss, 1e-24f));
    t *= (is_k ? ks : qs)[d];

    float partner = __shfl_xor(t, 32);
    float rh = (d < 32) ? -partner : partner;       // rotate_half

    const float fi = (float)(d & 31);
    float inv_freq = __builtin_amdgcn_exp2f(fi * -0.4152410118609203f);
    float pos = (float)s * inv_freq;
    float rev = pos * 0.15915494309189535f;         // v_sin takes revolutions
    rev = rev - floorf(rev);
    float sn = __builtin_amdgcn_sinf(rev);
    float cs = __builtin_amdgcn_cosf(rev);
    float base = (2.0f * fi + 25.6f) * (1.0f / 89.6f);
    float power = ((float)s - 1024.0f) * (1.0f / 512.0f);
    if (is_k) power = -power;
    float xsc = __builtin_amdgcn_exp2f(power * __builtin_amdgcn_logf(base));
    ptr[d] = (bf16)((t * cs + rh * sn) * xsc);
}

// ---------------------------------------------------------------------------
// Flash attention, no-max softmax (|score|/8 <= ~19 -> exp <= 1.4e8, fp32-safe;
// 0.125*log2e folded into Q; P = exp2). Row-sums via ones-column MFMA.
//
// ZERO-MOVEMENT P (R4): permuted Ks rows make the swapped-QK^T output land
// exactly in the PV A-fragment; exp2 feeds MFMA operands directly.
// bh-clustered XCD remap (R6): K/V L2-resident per XCD.
// R6 loop structure (R7's counted-vmcnt regressed -> reverted).
// QBLK wave = 16 q-rows (R8): more independent chains.
//
// R9: 8-WAVE BLOCKS (512 thr, QBLK=128). R8 confirmed TLP is the lever
// (occupancy 24->40, VALUBusy 44->55) but 256-thr blocks cap at 5 resident
// blocks = 20 waves/CU. 512-thr blocks: same 32KB LDS serves 8 waves ->
// 4 blocks x 8 waves = 32 waves/CU (100% theoretical). Staging per thread
// halves (512 threads cover a 64x64 tile in one pass: 1 K + 1 V async16
// per thread per tile). Grid 1024 (4/CU, bh-clustered: 8 bh x 16 qblk/XCD).
// ---------------------------------------------------------------------------
__device__ __forceinline__ int swz_a(int r) {
    int a = (r >> 3) & 3;
    return (r & 7) ^ a ^ ((a << 1) & 7);
}

__device__ __forceinline__ void attn_stage(
    const bf16* __restrict__ Kp, const bf16* __restrict__ Vp, int kt,
    char* kB, char* vB, int tid, int wave)
{
    int r = tid >> 3;                     // 512 threads -> rows 0..63
    int cbs = ((tid & 7) ^ swz_a(r)) << 3;
    int cu = wave << 6;                   // wave-uniform chunk base
    async16(&Kp[(size_t)(kt + r) * 64 + cbs], kB + (size_t)cu * 16);
    async16(&Vp[(size_t)r * 2048 + kt + cbs], vB + (size_t)cu * 16);
}

__global__ __launch_bounds__(512) void attn(
    const bf16* __restrict__ Q, const bf16* __restrict__ Kb,
    const bf16* __restrict__ VT, bf16* __restrict__ O)
{
    __shared__ bf16 Ks[2][64 * 64];
    __shared__ bf16 Vt[2][64 * 64];       // Vt[d][j] image (swizzled chunks)
    const int tid = threadIdx.x;
    const int lane = tid & 63, wave = tid >> 6;   // 8 waves
    const int quad = lane >> 4, l16 = lane & 15;
    const int wgi = blockIdx.x;           // 1024 blocks
    const int rr = wgi >> 3;              // 0..127 (per-XCD index)
    const int bh = ((wgi & 7) << 3) + (rr >> 4);   // bh-clustered per XCD
    const int q0 = (rr & 15) << 7;        // 128-row q block
    const int s_base = q0 + (wave << 4);  // wave owns 16 q-rows
    const bf16* Qp = Q + ((size_t)bh << 17);
    const bf16* Kp = Kb + ((size_t)bh << 17);
    const bf16* Vp = VT + ((size_t)bh << 17);

    bf16x8 qf[2];
    {
        const bf16* qrow = Qp + (size_t)(s_base + l16) * 64;
        qf[0] = *(const bf16x8*)&qrow[(quad << 3)];
        qf[1] = *(const bf16x8*)&qrow[32 + (quad << 3)];
        for (int j = 0; j < 8; ++j) {     // fold 0.125 * log2(e)
            qf[0][j] = (bf16)((float)qf[0][j] * 0.1803368801f);
            qf[1][j] = (bf16)((float)qf[1][j] * 0.1803368801f);
        }
    }
    bf16x8 ones = {};
    if (l16 == 0) for (int j = 0; j < 8; ++j) ones[j] = (bf16)1.0f;

    f32x4 oacc[4] = {};
    f32x4 lacc = {};

    // prologue: stage tile 0 into buffer 0
    attn_stage(Kp, Vp, 0, (char*)&Ks[0][0], (char*)&Vt[0][0], tid, wave);

    int buf = 0;
    for (int kt = 0; kt < 2048; kt += 64, buf ^= 1) {
        // barrier: drains vmcnt -> tile kt resident in buf; all waves are
        // also done reading buf^1 (prev iteration's compute precedes this
        // barrier in program order) so it is safe to overwrite.
        __syncthreads();
        if (kt + 64 < 2048)
            attn_stage(Kp, Vp, kt + 64,
                       (char*)&Ks[buf ^ 1][0], (char*)&Vt[buf ^ 1][0], tid, wave);

        const bf16* Kt_ = &Ks[buf][0];
        const bf16* Vc_ = &Vt[buf][0];

        // QK^T with permuted A-rows; exp2 lands directly in PV fragments.
        bf16x8 pf0, pf1;
        for (int nt = 0; nt < 4; ++nt) {
            const int g = ((l16 >> 2) << 3) + (l16 & 3)
                        + ((nt & 1) << 2) + ((nt >> 1) << 5);
            const int gs = swz_a(g);
            bf16x8 kf0 = *(const bf16x8*)&Kt_[(g << 6) + ((quad ^ gs) << 3)];
            bf16x8 kf1 = *(const bf16x8*)&Kt_[(g << 6) + (((quad + 4) ^ gs) << 3)];
            __builtin_amdgcn_s_setprio(1);
            f32x4 z = {};
            z = MFMA(kf0, qf[0], z);
            z = MFMA(kf1, qf[1], z);
            __builtin_amdgcn_s_setprio(0);
            // slot (quad,r) = P[q=l16][k = 8*quad + 4*(nt&1) + r + 32*(nt>>1)]
            bf16x8& dst = (nt < 2) ? pf0 : pf1;
            const int jb = (nt & 1) << 2;
            for (int r = 0; r < 4; ++r)
                dst[jb + r] = (bf16)__builtin_amdgcn_exp2f(z[r]);
        }

        __builtin_amdgcn_s_setprio(1);
        for (int ntd = 0; ntd < 4; ++ntd) {
            int row = (ntd << 4) + l16;
            int vs = swz_a(row);
            bf16x8 vf0 = *(const bf16x8*)&Vc_[(row << 6) + ((quad ^ vs) << 3)];
            bf16x8 vf1 = *(const bf16x8*)&Vc_[(row << 6) + (((quad + 4) ^ vs) << 3)];
            oacc[ntd] = MFMA(pf0, vf0, oacc[ntd]);
            oacc[ntd] = MFMA(pf1, vf1, oacc[ntd]);
        }
        lacc = MFMA(pf0, ones, lacc);
        lacc = MFMA(pf1, ones, lacc);
        __builtin_amdgcn_s_setprio(0);
    }

    const int b = bh >> 4, h = bh & 15;
    for (int r = 0; r < 4; ++r) {
        float l = __shfl(lacc[r], quad << 4);   // col-0 lane of quad
        float inv_l = 1.0f / l;
        int srow = s_base + (quad << 2) + r;
        for (int ntd = 0; ntd < 4; ++ntd) {
            int d = (ntd << 4) + l16;
            O[((((size_t)b * 2048 + srow) * 16) + h) * 64 + d] =
                (bf16)(oacc[ntd][r] * inv_l);
        }
    }
}

// ---------------------------------------------------------------------------
// LayerNorm over rows of [8192, 1024]; gamma/beta fp32.
// ---------------------------------------------------------------------------
__global__ __launch_bounds__(256) void layernorm(
    const bf16* __restrict__ x, const float* __restrict__ g,
    const float* __restrict__ b, bf16* __restrict__ y)
{
    __shared__ float red[8];
    const int row = blockIdx.x;
    const int t = threadIdx.x;
    const bf16* xr = x + ((size_t)row << 10);
    bf16x4 xv = *(const bf16x4*)&xr[t << 2];
    float v[4], s = 0.0f, sq = 0.0f;
    for (int i = 0; i < 4; ++i) { v[i] = (float)xv[i]; s += v[i]; sq += v[i] * v[i]; }
    for (int o = 1; o < 64; o <<= 1) { s += __shfl_xor(s, o); sq += __shfl_xor(sq, o); }
    const int wave = t >> 6, lane = t & 63;
    if (lane == 0) { red[wave] = s; red[4 + wave] = sq; }
    __syncthreads();
    s  = red[0] + red[1] + red[2] + red[3];
    sq = red[4] + red[5] + red[6] + red[7];
    float mu = s * (1.0f / 1024.0f);
    float var = fmaxf(sq * (1.0f / 1024.0f) - mu * mu, 0.0f);
    float rstd = rsqrtf(var + 1e-5f);
    bf16x4 ov;
    for (int i = 0; i < 4; ++i) {
        int c = (t << 2) + i;
        ov[i] = (bf16)((v[i] - mu) * rstd * g[c] + b[c]);
    }
    *(bf16x4*)(y + ((size_t)row << 10) + (t << 2)) = ov;
}

// ---------------------------------------------------------------------------
// Orchestration. ws layout (bytes), peak 92 MiB:
//   W2T 0..4M | ln 4..20M (q_bf16 before LN phase) | W1T 20..28M
//   q 28..44M k 44..60M vt 60..76M
//   WqkvT 76..82M (dead after QKV gemm) | attn 76..92M (overlay WqkvT)
//   h 28..60M [8192][2048] bf16 (overlay q/k after LN consumed attn)
// ---------------------------------------------------------------------------
extern "C" void kernel_launch(void* const* d_in, const int* in_sizes, int n_in,
                              void* d_out, int out_size, void* d_ws, size_t ws_size,
                              hipStream_t stream) {
    (void)in_sizes; (void)n_in; (void)out_size;
    const float* q    = (const float*)d_in[0];
    const float* Wqkv = (const float*)d_in[3];
    const float* bqkv = (const float*)d_in[4];
    const float* qsc  = (const float*)d_in[5];
    const float* ksc  = (const float*)d_in[6];
    const float* lng  = (const float*)d_in[7];
    const float* lnb  = (const float*)d_in[8];
    const float* W1   = (const float*)d_in[9];
    const float* b1   = (const float*)d_in[10];
    const float* W2   = (const float*)d_in[11];
    const float* b2   = (const float*)d_in[12];
    float* out = (float*)d_out;

    const size_t MB = 1024 * 1024;
    if (ws_size < 92 * MB) {
        fill_sentinel<<<8192, 256, 0, stream>>>(out);
        return;
    }

    char* ws = (char*)d_ws;
    bf16* W2T      = (bf16*)(ws + 0);
    bf16* ln_buf   = (bf16*)(ws + 4  * MB);
    bf16* q_bf     = (bf16*)(ws + 4  * MB);  // overlays ln_buf (dead pre-LN)
    bf16* W1T      = (bf16*)(ws + 20 * MB);
    bf16* q_buf    = (bf16*)(ws + 28 * MB);
    bf16* k_buf    = (bf16*)(ws + 44 * MB);
    bf16* vt_buf   = (bf16*)(ws + 60 * MB);  // V written transposed by QKV gemm
    bf16* WqkvT    = (bf16*)(ws + 76 * MB);
    bf16* attn_buf = (bf16*)(ws + 76 * MB);  // overlays WqkvT (dead post-QKV)
    bf16* h_buf    = (bf16*)(ws + 28 * MB);  // [8192][2048], overlays q/k

    convert_f32_bf16<<<4096, 256, 0, stream>>>(q, q_bf);
    transpose_f32_bf16<<<512,  256, 0, stream>>>(W2,   W2T,   2048, 1024);
    transpose_f32_bf16<<<1024, 256, 0, stream>>>(W1,   W1T,   1024, 4096);
    transpose_f32_bf16<<<768,  256, 0, stream>>>(Wqkv, WqkvT, 1024, 3072);

    // QKV: [8192,1024] @ [1024,3072] -> scatter q/k + V transposed.
    // BN=128: 32*24=768 (3/CU)
    gemm256<0, 128><<<768, 512, 0, stream>>>(q_bf, WqkvT, bqkv, 8192, 3072, 1024, 1024,
                                             q_buf, k_buf, vt_buf, nullptr, nullptr);
    norm_rope<<<65536, 256, 0, stream>>>(q_buf, k_buf, qsc, ksc);
    attn<<<1024, 512, 0, stream>>>(q_buf, k_buf, vt_buf, attn_buf);
    layernorm<<<8192, 256, 0, stream>>>(attn_buf, lng, lnb, ln_buf);
    // FF1 + fused SwiGLU: [8192,1024] @ [1024,4096] -> silu(gate)*x [8192,2048]
    // BN=256 split tiles: 32*16=512 blocks (2/CU)
    gemm256<3, 256><<<512, 512, 0, stream>>>(ln_buf, W1T, b1, 8192, 2048, 1024, 1024,
                                             h_buf, nullptr, nullptr, nullptr, nullptr);
    // FF2: [8192,2048] @ [2048,1024] + resid. BN=128: 32*8=256 (1/CU)
    gemm256<2, 128><<<256, 512, 0, stream>>>(h_buf, W2T, b2, 8192, 1024, 2048, 2048,
                                             nullptr, nullptr, nullptr, out, ln_buf);
}